// Round 1
// baseline (203.118 us; speedup 1.0000x reference)
//
#include <hip/hip_runtime.h>

// CRF forward (logZ) — B=1024 chains, T=256 steps, N=64 labels.
// One wave per batch chain; lane k owns label k. Per step:
//   w_j = exp(alpha_j - c);  s_k = sum_j w_j * E[j,k];
//   alpha_k = log(s_k) + c + colmax_k + emit[t,k]
// where E[j,k] = exp(trans_n[j,k] - colmax_k) is precomputed (t-invariant).

#define CRF_B 1024
#define CRF_T 256
#define CRF_N 64

__device__ __forceinline__ float wave_readlane0(float x) {
    return __int_as_float(__builtin_amdgcn_readfirstlane(__float_as_int(x)));
}

__launch_bounds__(256, 1)
__global__ void crf_fwd_kernel(const float* __restrict__ emit,
                               const float* __restrict__ trans,
                               const float* __restrict__ strans,
                               const float* __restrict__ etrans,
                               const unsigned char* __restrict__ mask_u8,
                               float* __restrict__ out)
{
    __shared__ float tn[CRF_N * CRF_N];     // trans - row_lse  (natural log)
    __shared__ float Et[CRF_N * 68];        // E transposed: Et[k*68 + j], padded stride
    __shared__ float colmax_s[CRF_N];
    __shared__ float rowlse_s[CRF_N];
    __shared__ float snorm_s[2];            // lse(strans), lse(etrans)
    __shared__ float wbuf[4][CRF_N];

    const int tid  = threadIdx.x;
    const int lane = tid & 63;
    const int wid  = tid >> 6;

    // ---------- preprocess (redundant per block; tiny, L2-cached) ----------
    if (tid < CRF_N) {
        const float* row = trans + tid * CRF_N;
        float m = -1e30f;
        for (int k = 0; k < CRF_N; ++k) m = fmaxf(m, row[k]);
        float s = 0.f;
        for (int k = 0; k < CRF_N; ++k) s += __expf(row[k] - m);
        rowlse_s[tid] = m + __logf(s);
    }
    if (tid == 64) {
        float m = -1e30f;
        for (int k = 0; k < CRF_N; ++k) m = fmaxf(m, strans[k]);
        float s = 0.f;
        for (int k = 0; k < CRF_N; ++k) s += __expf(strans[k] - m);
        snorm_s[0] = m + __logf(s);
    }
    if (tid == 65) {
        float m = -1e30f;
        for (int k = 0; k < CRF_N; ++k) m = fmaxf(m, etrans[k]);
        float s = 0.f;
        for (int k = 0; k < CRF_N; ++k) s += __expf(etrans[k] - m);
        snorm_s[1] = m + __logf(s);
    }
    __syncthreads();

    #pragma unroll
    for (int i = 0; i < 16; ++i) {
        int c = i * 256 + tid;
        int r = c >> 6;
        tn[c] = trans[c] - rowlse_s[r];
    }
    __syncthreads();

    if (tid < CRF_N) {
        float m = -1e30f;
        for (int j = 0; j < CRF_N; ++j) m = fmaxf(m, tn[j * CRF_N + tid]);
        colmax_s[tid] = m;
    }
    __syncthreads();

    #pragma unroll
    for (int i = 0; i < 16; ++i) {
        int c = i * 256 + tid;
        int r = c >> 6, col = c & 63;
        Et[col * 68 + r] = __expf(tn[c] - colmax_s[col]);
    }
    __syncthreads();

    // ---------- per-wave state ----------
    // E column for this lane: E[j][lane], j = 0..63, in registers.
    float Ecol[64];
    #pragma unroll
    for (int i = 0; i < 16; ++i) {
        float4 v = *(const float4*)&Et[lane * 68 + i * 4];
        Ecol[4 * i + 0] = v.x;
        Ecol[4 * i + 1] = v.y;
        Ecol[4 * i + 2] = v.z;
        Ecol[4 * i + 3] = v.w;
    }

    const int b = blockIdx.x * 4 + wid;

    // ---- sequence length from mask (dtype-adaptive: bool bytes vs int32) ----
    int len;
    {
        int c8 = 0;
        #pragma unroll
        for (int q = 0; q < 4; ++q)
            c8 += (mask_u8[(size_t)b * CRF_T + q * 64 + lane] != 0) ? 1 : 0;
        for (int off = 1; off < 64; off <<= 1) c8 += __shfl_xor(c8, off);
        // genuine bool rows have len in [128,256]; int32-as-bytes gives <= 64
        if (c8 >= 128) {
            len = c8;
        } else {
            const int* mi = (const int*)mask_u8;
            int ci = 0;
            #pragma unroll
            for (int q = 0; q < 4; ++q)
                ci += (mi[(size_t)b * CRF_T + q * 64 + lane] != 0) ? 1 : 0;
            for (int off = 1; off < 64; off <<= 1) ci += __shfl_xor(ci, off);
            len = ci;
        }
    }

    const float* eb  = emit + (size_t)b * CRF_T * CRF_N;
    const float cmx  = colmax_s[lane];
    const float sn   = snorm_s[0];
    const float en   = snorm_s[1];

    float alpha = (strans[lane] - sn) + eb[lane];
    float c     = wave_readlane0(alpha);

    float e_cur = eb[CRF_N + lane];   // t = 1 emission (len >= 128 > 1 always)

    for (int t = 1; t < len; ++t) {
        // prefetch next emission (clamped so the last iter re-reads current)
        int t_nx = (t + 1 < len) ? (t + 1) : t;
        float e_nxt = eb[(size_t)t_nx * CRF_N + lane];

        float w = __expf(alpha - c);
        wbuf[wid][lane] = w;
        __builtin_amdgcn_wave_barrier();   // keep write before broadcast reads

        float s0 = 0.f, s1 = 0.f, s2 = 0.f, s3 = 0.f;
        #pragma unroll
        for (int i = 0; i < 16; ++i) {
            float4 wv = *(const float4*)&wbuf[wid][i * 4];  // wave-broadcast read
            s0 = fmaf(wv.x, Ecol[4 * i + 0], s0);
            s1 = fmaf(wv.y, Ecol[4 * i + 1], s1);
            s2 = fmaf(wv.z, Ecol[4 * i + 2], s2);
            s3 = fmaf(wv.w, Ecol[4 * i + 3], s3);
        }
        float s = (s0 + s1) + (s2 + s3);

        alpha = __logf(s) + c + cmx + e_cur;
        c = wave_readlane0(alpha);
        e_cur = e_nxt;
    }

    // ---------- final lse over labels + batch-sum ----------
    float v = alpha + (etrans[lane] - en);
    float m = v;
    for (int off = 1; off < 64; off <<= 1) m = fmaxf(m, __shfl_xor(m, off));
    float sum = __expf(v - m);
    for (int off = 1; off < 64; off <<= 1) sum += __shfl_xor(sum, off);

    if (lane == 0) {
        float logZb = m + __logf(sum);
        atomicAdd(out, logZb);
    }
}

extern "C" void kernel_launch(void* const* d_in, const int* in_sizes, int n_in,
                              void* d_out, int out_size, void* d_ws, size_t ws_size,
                              hipStream_t stream) {
    const float* emit   = (const float*)d_in[0];
    const float* trans  = (const float*)d_in[1];
    const float* strans = (const float*)d_in[2];
    const float* etrans = (const float*)d_in[3];
    const unsigned char* mask = (const unsigned char*)d_in[4];
    float* out = (float*)d_out;

    hipMemsetAsync(out, 0, sizeof(float), stream);
    crf_fwd_kernel<<<dim3(CRF_B / 4), dim3(256), 0, stream>>>(
        emit, trans, strans, etrans, mask, out);
}

// Round 2
// 186.620 us; speedup vs baseline: 1.0884x; 1.0884x over previous
//
#include <hip/hip_runtime.h>

// CRF forward (logZ) — B=1024 chains, T=256 steps, N=64 labels.
// One wave per batch chain; lane k owns label k.
// Chain-minimized recursion: broadcast unnormalized u via LDS;
//   s'_k = sum_j u_j(t-1) * E[j,k]            (packed f32 FMA tree)
//   u_k(t) = s'_k * (R(t-1) * ee_k(t))        (one mul; R*ee precomputed off-chain)
// where ee_k(t) = exp(emit[t,k] + colmax_k) from an 8-deep prefetch FIFO,
// R(t) = rcp(u_0(t)) and Lacc += log(u_0(t)) run on the side chain.
// Exact lse recursion with shift c(t) = alpha_0(t).

#define CRF_B 1024
#define CRF_T 256
#define CRF_N 64

typedef float v2f __attribute__((ext_vector_type(2)));

__device__ __forceinline__ float rl0(float x) {
    return __int_as_float(__builtin_amdgcn_readfirstlane(__float_as_int(x)));
}

__launch_bounds__(256, 1)
__global__ void crf_fwd_kernel(const float* __restrict__ emit,
                               const float* __restrict__ trans,
                               const float* __restrict__ strans,
                               const float* __restrict__ etrans,
                               const unsigned char* __restrict__ mask_u8,
                               float* __restrict__ out)
{
    __shared__ float tn[CRF_N * CRF_N];
    __shared__ float Et[CRF_N * 68];        // E^T: Et[k*68 + j], padded stride
    __shared__ float colmax_s[CRF_N];
    __shared__ float rowlse_s[CRF_N];
    __shared__ float snorm_s[2];
    __shared__ float ubuf[4][2][CRF_N];     // [wave][pingpong][lane]

    const int tid  = threadIdx.x;
    const int lane = tid & 63;
    const int wid  = tid >> 6;

    // ---------- preprocess (redundant per block; tiny, L2/L3-cached) ----------
    if (tid < CRF_N) {
        const float* row = trans + tid * CRF_N;
        float m = -1e30f;
        for (int k = 0; k < CRF_N; ++k) m = fmaxf(m, row[k]);
        float s = 0.f;
        for (int k = 0; k < CRF_N; ++k) s += __expf(row[k] - m);
        rowlse_s[tid] = m + __logf(s);
    }
    if (tid == 64) {
        float m = -1e30f;
        for (int k = 0; k < CRF_N; ++k) m = fmaxf(m, strans[k]);
        float s = 0.f;
        for (int k = 0; k < CRF_N; ++k) s += __expf(strans[k] - m);
        snorm_s[0] = m + __logf(s);
    }
    if (tid == 65) {
        float m = -1e30f;
        for (int k = 0; k < CRF_N; ++k) m = fmaxf(m, etrans[k]);
        float s = 0.f;
        for (int k = 0; k < CRF_N; ++k) s += __expf(etrans[k] - m);
        snorm_s[1] = m + __logf(s);
    }
    __syncthreads();

    #pragma unroll
    for (int i = 0; i < 16; ++i) {
        int c = i * 256 + tid;
        int r = c >> 6;
        tn[c] = trans[c] - rowlse_s[r];
    }
    __syncthreads();

    if (tid < CRF_N) {
        float m = -1e30f;
        for (int j = 0; j < CRF_N; ++j) m = fmaxf(m, tn[j * CRF_N + tid]);
        colmax_s[tid] = m;
    }
    __syncthreads();

    #pragma unroll
    for (int i = 0; i < 16; ++i) {
        int c = i * 256 + tid;
        int r = c >> 6, col = c & 63;
        Et[col * 68 + r] = __expf(tn[c] - colmax_s[col]);
    }
    __syncthreads();

    // ---------- per-wave state ----------
    // E column for this lane as 32 packed pairs: Ecol2[2i] = {E[4i],E[4i+1]}, etc.
    v2f Ecol2[32];
    #pragma unroll
    for (int i = 0; i < 16; ++i) {
        float4 v = *(const float4*)&Et[lane * 68 + i * 4];
        v2f lo; lo[0] = v.x; lo[1] = v.y;
        v2f hi; hi[0] = v.z; hi[1] = v.w;
        Ecol2[2 * i]     = lo;
        Ecol2[2 * i + 1] = hi;
    }

    const int b = blockIdx.x * 4 + wid;

    // ---- sequence length from mask (dtype-adaptive: bool bytes vs int32) ----
    int len;
    {
        int c8 = 0;
        #pragma unroll
        for (int q = 0; q < 4; ++q)
            c8 += (mask_u8[(size_t)b * CRF_T + q * 64 + lane] != 0) ? 1 : 0;
        for (int off = 1; off < 64; off <<= 1) c8 += __shfl_xor(c8, off);
        if (c8 >= 128) {
            len = c8;       // genuine bool bytes (len in [128,256])
        } else {
            const int* mi = (const int*)mask_u8;
            int ci = 0;
            #pragma unroll
            for (int q = 0; q < 4; ++q)
                ci += (mi[(size_t)b * CRF_T + q * 64 + lane] != 0) ? 1 : 0;
            for (int off = 1; off < 64; off <<= 1) ci += __shfl_xor(ci, off);
            len = ci;
        }
    }

    const float* eb = emit + (size_t)b * CRF_T * CRF_N;
    const float cmx = colmax_s[lane];
    const float sn  = snorm_s[0];
    const float en  = snorm_s[1];

    // init (t = 0)
    float alpha0 = (strans[lane] - sn) + eb[lane];
    float c0 = rl0(alpha0);
    float u  = __expf(alpha0 - c0);   // lane 0: u = 1
    float R  = 1.0f;                  // rcp(readfirstlane(u))
    float Lacc = c0;                  // running shift c(t-1)
    ubuf[wid][0][lane] = u;
    __builtin_amdgcn_wave_barrier();

    // one step: read slot P, write slot P^1
#define CRF_STEP(EE, P)                                                        \
    {                                                                          \
        const float* ub = &ubuf[wid][(P)][0];                                  \
        v2f a0 = {0.f, 0.f}, a1 = {0.f, 0.f}, a2 = {0.f, 0.f}, a3 = {0.f, 0.f};\
        _Pragma("unroll")                                                      \
        for (int i = 0; i < 16; i += 2) {                                      \
            float4 w0 = *(const float4*)(ub + 4 * i);                          \
            float4 w1 = *(const float4*)(ub + 4 * i + 4);                      \
            v2f p0; p0[0] = w0.x; p0[1] = w0.y;                                \
            v2f p1; p1[0] = w0.z; p1[1] = w0.w;                                \
            v2f p2; p2[0] = w1.x; p2[1] = w1.y;                                \
            v2f p3; p3[0] = w1.z; p3[1] = w1.w;                                \
            a0 = __builtin_elementwise_fma(p0, Ecol2[2 * i],     a0);          \
            a1 = __builtin_elementwise_fma(p1, Ecol2[2 * i + 1], a1);          \
            a2 = __builtin_elementwise_fma(p2, Ecol2[2 * i + 2], a2);          \
            a3 = __builtin_elementwise_fma(p3, Ecol2[2 * i + 3], a3);          \
        }                                                                      \
        v2f aa = (a0 + a1) + (a2 + a3);                                        \
        float s = aa[0] + aa[1];                                               \
        u = s * (R * (EE));                                                    \
        float u0 = rl0(u);                                                     \
        ubuf[wid][(P) ^ 1][lane] = u;                                          \
        __builtin_amdgcn_wave_barrier();                                       \
        R = __builtin_amdgcn_rcpf(u0);                                         \
        Lacc += __logf(u0);                                                    \
    }

    // ---------- main loop: groups of 8 with deep prefetch ----------
    float eN[8], eeC[8];
    #pragma unroll
    for (int d = 0; d < 8; ++d) eN[d] = eb[(size_t)(1 + d) * CRF_N + lane];
    #pragma unroll
    for (int d = 0; d < 8; ++d) eeC[d] = __expf(eN[d] + cmx);

    int t0 = 1;
    while (t0 + 8 <= len) {
        // issue next group's loads (in flight across all 8 steps)
        #pragma unroll
        for (int d = 0; d < 8; ++d) {
            int ti = t0 + 8 + d;
            ti = (ti < len) ? ti : (len - 1);
            eN[d] = eb[(size_t)ti * CRF_N + lane];
        }
        CRF_STEP(eeC[0], 0); CRF_STEP(eeC[1], 1);
        CRF_STEP(eeC[2], 0); CRF_STEP(eeC[3], 1);
        CRF_STEP(eeC[4], 0); CRF_STEP(eeC[5], 1);
        CRF_STEP(eeC[6], 0); CRF_STEP(eeC[7], 1);
        #pragma unroll
        for (int d = 0; d < 8; ++d) eeC[d] = __expf(eN[d] + cmx);
        t0 += 8;
    }
    // tail (< 8 steps): eeC already holds t0..t0+7
    {
        const int nrem = len - t0;   // wave-uniform
        #pragma unroll
        for (int d = 0; d < 8; ++d) {
            if (d >= nrem) break;
            if (d & 1) { CRF_STEP(eeC[d], 1); }
            else       { CRF_STEP(eeC[d], 0); }
        }
    }
#undef CRF_STEP

    // ---------- final lse over labels + batch-sum ----------
    // alpha_k(last) = Lacc + log(u_k * R_final)
    float v = Lacc + __logf(u * R) + (etrans[lane] - en);
    float m = v;
    for (int off = 1; off < 64; off <<= 1) m = fmaxf(m, __shfl_xor(m, off));
    float sum = __expf(v - m);
    for (int off = 1; off < 64; off <<= 1) sum += __shfl_xor(sum, off);

    if (lane == 0) {
        atomicAdd(out, m + __logf(sum));
    }
}

extern "C" void kernel_launch(void* const* d_in, const int* in_sizes, int n_in,
                              void* d_out, int out_size, void* d_ws, size_t ws_size,
                              hipStream_t stream) {
    const float* emit   = (const float*)d_in[0];
    const float* trans  = (const float*)d_in[1];
    const float* strans = (const float*)d_in[2];
    const float* etrans = (const float*)d_in[3];
    const unsigned char* mask = (const unsigned char*)d_in[4];
    float* out = (float*)d_out;

    hipMemsetAsync(out, 0, sizeof(float), stream);
    crf_fwd_kernel<<<dim3(CRF_B / 4), dim3(256), 0, stream>>>(
        emit, trans, strans, etrans, mask, out);
}

// Round 3
// 167.178 us; speedup vs baseline: 1.2150x; 1.1163x over previous
//
#include <hip/hip_runtime.h>

// CRF forward (logZ) — B=1024 chains, T=256 steps, N=64 labels.
// One wave per batch chain; lane k owns label k. No LDS anywhere.
// Broadcast of u across lanes via v_readlane (private VALU pipe, no LDS
// latency/contention):   s_k = sum_j readlane(u, j) * Ecol[j]
//   u_k(t) = s_k * (R(t-1) * ee_k(t)),  ee = exp(emit + cmx) from an
// 8-deep prefetch FIFO; R = rcp(u_0), Lacc += log(u_0) on the side chain.
// Exact lse recursion with shift c(t) = alpha_0(t).

#define CRF_B 1024
#define CRF_T 256
#define CRF_N 64

__device__ __forceinline__ float rl0(float x) {
    return __int_as_float(__builtin_amdgcn_readfirstlane(__float_as_int(x)));
}
__device__ __forceinline__ float rlane(float x, int j) {
    return __int_as_float(__builtin_amdgcn_readlane(__float_as_int(x), j));
}

__device__ __forceinline__ float wave_lse(float v) {
    float m = v;
    #pragma unroll
    for (int off = 1; off < 64; off <<= 1) m = fmaxf(m, __shfl_xor(m, off));
    float s = __expf(v - m);
    #pragma unroll
    for (int off = 1; off < 64; off <<= 1) s += __shfl_xor(s, off);
    return m + __logf(s);
}

__launch_bounds__(256, 1)
__attribute__((amdgpu_waves_per_eu(1, 1)))
__global__ void crf_fwd_kernel(const float* __restrict__ emit,
                               const float* __restrict__ trans,
                               const float* __restrict__ strans,
                               const float* __restrict__ etrans,
                               const unsigned char* __restrict__ mask_u8,
                               float* __restrict__ out)
{
    const int tid  = threadIdx.x;
    const int lane = tid & 63;
    const int wid  = tid >> 6;
    const int b    = blockIdx.x * 4 + wid;

    // ---------- register-only preprocess (per wave) ----------
    // rowlse for row = lane
    float rowlse_v;
    {
        const float* rowp = trans + lane * CRF_N;
        float m = -1e30f;
        #pragma unroll 8
        for (int k = 0; k < CRF_N; ++k) m = fmaxf(m, rowp[k]);
        float s = 0.f;
        #pragma unroll 8
        for (int k = 0; k < CRF_N; ++k) s += __expf(rowp[k] - m);
        rowlse_v = m + __logf(s);
    }

    // column for this lane: Ecol[j] = exp(trans[j][lane] - rowlse_j - cmx)
    float Ecol[CRF_N];
    #pragma unroll
    for (int j = 0; j < CRF_N; ++j)
        Ecol[j] = trans[j * CRF_N + lane] - rlane(rowlse_v, j);
    float cmx = -1e30f;
    #pragma unroll
    for (int j = 0; j < CRF_N; ++j) cmx = fmaxf(cmx, Ecol[j]);
    #pragma unroll
    for (int j = 0; j < CRF_N; ++j) Ecol[j] = __expf(Ecol[j] - cmx);

    const float sn = wave_lse(strans[lane]);

    // ---- sequence length from mask (dtype-adaptive: bool bytes vs int32) ----
    int len;
    {
        int c8 = 0;
        #pragma unroll
        for (int q = 0; q < 4; ++q)
            c8 += (mask_u8[(size_t)b * CRF_T + q * 64 + lane] != 0) ? 1 : 0;
        for (int off = 1; off < 64; off <<= 1) c8 += __shfl_xor(c8, off);
        if (c8 >= 128) {
            len = c8;       // genuine bool bytes (len in [128,256])
        } else {
            const int* mi = (const int*)mask_u8;
            int ci = 0;
            #pragma unroll
            for (int q = 0; q < 4; ++q)
                ci += (mi[(size_t)b * CRF_T + q * 64 + lane] != 0) ? 1 : 0;
            for (int off = 1; off < 64; off <<= 1) ci += __shfl_xor(ci, off);
            len = ci;
        }
    }

    const float* eb = emit + (size_t)b * CRF_T * CRF_N;

    // ---------- init (t = 0) ----------
    float alpha0 = (strans[lane] - sn) + eb[lane];
    float c0 = rl0(alpha0);
    float u  = __expf(alpha0 - c0);   // lane 0: u = 1
    float R  = 1.0f;                  // rcp(readfirstlane(u))
    float Lacc = c0;                  // running log-shift

    // one step: readlane-broadcast dot on the VALU pipe
#define CRF_STEP(EE)                                                    \
    {                                                                   \
        float s0 = 0.f, s1 = 0.f, s2 = 0.f, s3 = 0.f;                   \
        _Pragma("unroll")                                               \
        for (int j = 0; j < CRF_N; j += 4) {                            \
            s0 = fmaf(rlane(u, j + 0), Ecol[j + 0], s0);                \
            s1 = fmaf(rlane(u, j + 1), Ecol[j + 1], s1);                \
            s2 = fmaf(rlane(u, j + 2), Ecol[j + 2], s2);                \
            s3 = fmaf(rlane(u, j + 3), Ecol[j + 3], s3);                \
        }                                                               \
        float s = (s0 + s1) + (s2 + s3);                                \
        u = s * (R * (EE));                                             \
        float u0 = rl0(u);                                              \
        R = __builtin_amdgcn_rcpf(u0);                                  \
        Lacc += __logf(u0);                                             \
    }

    // ---------- main loop: groups of 8 with deep emission prefetch ----------
    float eN[8], eeC[8];
    #pragma unroll
    for (int d = 0; d < 8; ++d) eN[d] = eb[(size_t)(1 + d) * CRF_N + lane];
    #pragma unroll
    for (int d = 0; d < 8; ++d) eeC[d] = __expf(eN[d] + cmx);

    int t0 = 1;
    while (t0 + 8 <= len) {
        #pragma unroll
        for (int d = 0; d < 8; ++d) {
            int ti = t0 + 8 + d;
            ti = (ti < len) ? ti : (len - 1);
            eN[d] = eb[(size_t)ti * CRF_N + lane];
        }
        CRF_STEP(eeC[0]); CRF_STEP(eeC[1]);
        CRF_STEP(eeC[2]); CRF_STEP(eeC[3]);
        CRF_STEP(eeC[4]); CRF_STEP(eeC[5]);
        CRF_STEP(eeC[6]); CRF_STEP(eeC[7]);
        #pragma unroll
        for (int d = 0; d < 8; ++d) eeC[d] = __expf(eN[d] + cmx);
        t0 += 8;
    }
    {
        const int nrem = len - t0;   // wave-uniform, < 8
        #pragma unroll
        for (int d = 0; d < 8; ++d) {
            if (d >= nrem) break;
            CRF_STEP(eeC[d]);
        }
    }
#undef CRF_STEP

    // ---------- final lse over labels + batch-sum ----------
    const float en = wave_lse(etrans[lane]);
    float v = Lacc + __logf(u * R) + (etrans[lane] - en);
    float m = v;
    #pragma unroll
    for (int off = 1; off < 64; off <<= 1) m = fmaxf(m, __shfl_xor(m, off));
    float sum = __expf(v - m);
    #pragma unroll
    for (int off = 1; off < 64; off <<= 1) sum += __shfl_xor(sum, off);

    if (lane == 0) {
        atomicAdd(out, m + __logf(sum));
    }
}

extern "C" void kernel_launch(void* const* d_in, const int* in_sizes, int n_in,
                              void* d_out, int out_size, void* d_ws, size_t ws_size,
                              hipStream_t stream) {
    const float* emit   = (const float*)d_in[0];
    const float* trans  = (const float*)d_in[1];
    const float* strans = (const float*)d_in[2];
    const float* etrans = (const float*)d_in[3];
    const unsigned char* mask = (const unsigned char*)d_in[4];
    float* out = (float*)d_out;

    hipMemsetAsync(out, 0, sizeof(float), stream);
    crf_fwd_kernel<<<dim3(CRF_B / 4), dim3(256), 0, stream>>>(
        emit, trans, strans, etrans, mask, out);
}

// Round 4
// 157.974 us; speedup vs baseline: 1.2858x; 1.0583x over previous
//
#include <hip/hip_runtime.h>

// CRF forward (logZ) — B=1024 chains, T=256 steps, N=64 labels.
// One wave per batch chain; lane k owns label k. No LDS.
//   s_k = sum_j readlane(u, j) * Ecol[j]   (batched readlanes: 16 broadcasts
//                                           then 16 FMAs -> no SGPR hazards)
//   u_k(t) = s_k * (R(t-1) * ee_k(t)),  ee = exp(emit + cmx), 4-deep prefetch.
// Normalizer tracked as a product Pm *= u0 with frexp renorm per 4 steps
// (replaces per-step log on the side chain). Exact lse recursion.

#define CRF_B 1024
#define CRF_T 256
#define CRF_N 64

__device__ __forceinline__ float rl0(float x) {
    return __int_as_float(__builtin_amdgcn_readfirstlane(__float_as_int(x)));
}
__device__ __forceinline__ float rlane(float x, int j) {
    return __int_as_float(__builtin_amdgcn_readlane(__float_as_int(x), j));
}

__device__ __forceinline__ float wave_lse(float v) {
    float m = v;
    #pragma unroll
    for (int off = 1; off < 64; off <<= 1) m = fmaxf(m, __shfl_xor(m, off));
    float s = __expf(v - m);
    #pragma unroll
    for (int off = 1; off < 64; off <<= 1) s += __shfl_xor(s, off);
    return m + __logf(s);
}

__launch_bounds__(256, 1)
__attribute__((amdgpu_waves_per_eu(1, 1)))
__global__ void crf_fwd_kernel(const float* __restrict__ emit,
                               const float* __restrict__ trans,
                               const float* __restrict__ strans,
                               const float* __restrict__ etrans,
                               const unsigned char* __restrict__ mask_u8,
                               float* __restrict__ out)
{
    const int tid  = threadIdx.x;
    const int lane = tid & 63;
    const int wid  = tid >> 6;
    const int b    = blockIdx.x * 4 + wid;

    // ---------- register-only preprocess (per wave) ----------
    float rowlse_v;
    {
        const float* rowp = trans + lane * CRF_N;
        float m = -1e30f;
        #pragma unroll 8
        for (int k = 0; k < CRF_N; ++k) m = fmaxf(m, rowp[k]);
        float s = 0.f;
        #pragma unroll 8
        for (int k = 0; k < CRF_N; ++k) s += __expf(rowp[k] - m);
        rowlse_v = m + __logf(s);
    }

    float Ecol[CRF_N];
    #pragma unroll
    for (int j = 0; j < CRF_N; ++j)
        Ecol[j] = trans[j * CRF_N + lane] - rlane(rowlse_v, j);
    float cmx = -1e30f;
    #pragma unroll
    for (int j = 0; j < CRF_N; ++j) cmx = fmaxf(cmx, Ecol[j]);
    #pragma unroll
    for (int j = 0; j < CRF_N; ++j) Ecol[j] = __expf(Ecol[j] - cmx);

    const float sn = wave_lse(strans[lane]);

    // ---- sequence length from mask (dtype-adaptive: bool bytes vs int32) ----
    int len;
    {
        int c8 = 0;
        #pragma unroll
        for (int q = 0; q < 4; ++q)
            c8 += (mask_u8[(size_t)b * CRF_T + q * 64 + lane] != 0) ? 1 : 0;
        for (int off = 1; off < 64; off <<= 1) c8 += __shfl_xor(c8, off);
        if (c8 >= 128) {
            len = c8;       // genuine bool bytes (len in [128,256])
        } else {
            const int* mi = (const int*)mask_u8;
            int ci = 0;
            #pragma unroll
            for (int q = 0; q < 4; ++q)
                ci += (mi[(size_t)b * CRF_T + q * 64 + lane] != 0) ? 1 : 0;
            for (int off = 1; off < 64; off <<= 1) ci += __shfl_xor(ci, off);
            len = ci;
        }
    }

    const float* eb = emit + (size_t)b * CRF_T * CRF_N;

    // ---------- init (t = 0) ----------
    float alpha0 = (strans[lane] - sn) + eb[lane];
    float c0 = rl0(alpha0);
    float u  = __expf(alpha0 - c0);   // lane 0: u = 1
    float R  = 1.0f;                  // rcp(readfirstlane(u))
    float Pm = 1.0f;                  // running product of u0 (mantissa part)
    int   Eacc = 0;                   // running exponent (base 2)
    const float c0_keep = c0;

    // one step: batched readlane broadcast (16 at a time), then FMAs
#define CRF_STEP(EE)                                                     \
    {                                                                    \
        float s0 = 0.f, s1 = 0.f, s2 = 0.f, s3 = 0.f;                    \
        _Pragma("unroll")                                                \
        for (int g = 0; g < 4; ++g) {                                    \
            float w[16];                                                 \
            _Pragma("unroll")                                            \
            for (int i = 0; i < 16; ++i) w[i] = rlane(u, 16 * g + i);    \
            _Pragma("unroll")                                            \
            for (int i = 0; i < 16; i += 4) {                            \
                s0 = fmaf(w[i + 0], Ecol[16 * g + i + 0], s0);           \
                s1 = fmaf(w[i + 1], Ecol[16 * g + i + 1], s1);           \
                s2 = fmaf(w[i + 2], Ecol[16 * g + i + 2], s2);           \
                s3 = fmaf(w[i + 3], Ecol[16 * g + i + 3], s3);           \
            }                                                            \
        }                                                                \
        float s = (s0 + s1) + (s2 + s3);                                 \
        u = s * (R * (EE));                                              \
        float u0 = rl0(u);                                               \
        R = __builtin_amdgcn_rcpf(u0);                                   \
        Pm *= u0;                                                        \
    }

    // ---------- main loop: groups of 4 with emission prefetch ----------
    float eN[4], eeC[4];
    #pragma unroll
    for (int d = 0; d < 4; ++d) eN[d] = eb[(size_t)(1 + d) * CRF_N + lane];
    #pragma unroll
    for (int d = 0; d < 4; ++d) eeC[d] = __expf(eN[d] + cmx);

    int t0 = 1;
    while (t0 + 4 <= len) {
        #pragma unroll
        for (int d = 0; d < 4; ++d) {
            int ti = t0 + 4 + d;
            ti = (ti < len) ? ti : (len - 1);
            eN[d] = eb[(size_t)ti * CRF_N + lane];
        }
        CRF_STEP(eeC[0]); CRF_STEP(eeC[1]);
        CRF_STEP(eeC[2]); CRF_STEP(eeC[3]);
        // renormalize the running product (keeps Pm in f32 range)
        {
            int ex;
            Pm = frexpf(Pm, &ex);
            Eacc += ex;
        }
        #pragma unroll
        for (int d = 0; d < 4; ++d) eeC[d] = __expf(eN[d] + cmx);
        t0 += 4;
    }
    {
        const int nrem = len - t0;   // wave-uniform, < 4
        #pragma unroll
        for (int d = 0; d < 4; ++d) {
            if (d >= nrem) break;
            CRF_STEP(eeC[d]);
        }
    }
#undef CRF_STEP

    // ---------- final lse over labels + batch-sum ----------
    const float en = wave_lse(etrans[lane]);
    float Lacc = c0_keep + 0.6931471805599453f * (float)Eacc + __logf(Pm);
    float v = Lacc + __logf(u * R) + (etrans[lane] - en);
    float m = v;
    #pragma unroll
    for (int off = 1; off < 64; off <<= 1) m = fmaxf(m, __shfl_xor(m, off));
    float sum = __expf(v - m);
    #pragma unroll
    for (int off = 1; off < 64; off <<= 1) sum += __shfl_xor(sum, off);

    if (lane == 0) {
        atomicAdd(out, m + __logf(sum));
    }
}

extern "C" void kernel_launch(void* const* d_in, const int* in_sizes, int n_in,
                              void* d_out, int out_size, void* d_ws, size_t ws_size,
                              hipStream_t stream) {
    const float* emit   = (const float*)d_in[0];
    const float* trans  = (const float*)d_in[1];
    const float* strans = (const float*)d_in[2];
    const float* etrans = (const float*)d_in[3];
    const unsigned char* mask = (const unsigned char*)d_in[4];
    float* out = (float*)d_out;

    hipMemsetAsync(out, 0, sizeof(float), stream);
    crf_fwd_kernel<<<dim3(CRF_B / 4), dim3(256), 0, stream>>>(
        emit, trans, strans, etrans, mask, out);
}

// Round 6
// 142.587 us; speedup vs baseline: 1.4245x; 1.1079x over previous
//
#include <hip/hip_runtime.h>

// CRF forward (logZ) — B=1024 chains, T=256 steps, N=64 labels.
// One 64-lane wave per chain; lane k owns label k. No LDS.
// Inner dot in bf16 pairs:  s_k = sum_m dot2(u_pair[m], E_pair[m][k])
//   32 readlanes (even lanes of packed u) + 32 v_dot2_f32_bf16 (f32 accum).
//   u_k(t) = s_k * (R(t-1)*ee_k(t)); R = rcp(u0), Pm *= u0 on the side chain
//   with u0 = rl0(s)*R*ee0 (fully off the broadcast critical path).
// Exact lse recursion with per-step scaling; only dot INPUTS are bf16.

#define CRF_B 1024
#define CRF_T 256
#define CRF_N 64

typedef __bf16 bf16x2 __attribute__((ext_vector_type(2)));

__device__ __forceinline__ float rl0(float x) {
    return __int_as_float(__builtin_amdgcn_readfirstlane(__float_as_int(x)));
}
__device__ __forceinline__ float rlanef(float x, int j) {
    return __int_as_float(__builtin_amdgcn_readlane(__float_as_int(x), j));
}

__device__ __forceinline__ float wave_lse(float v) {
    float m = v;
    #pragma unroll
    for (int off = 1; off < 64; off <<= 1) m = fmaxf(m, __shfl_xor(m, off));
    float s = __expf(v - m);
    #pragma unroll
    for (int off = 1; off < 64; off <<= 1) s += __shfl_xor(s, off);
    return m + __logf(s);
}

// f32 -> bf16 (round-to-nearest-even), low 16 bits of result
__device__ __forceinline__ unsigned bf16_rne(float f) {
    unsigned u = __float_as_uint(f);
    return (u + 0x7FFFu + ((u >> 16) & 1u)) >> 16;
}

// lane L: pack(bf16(u_L), bf16(u_{L^1})) — valid pairs read from EVEN lanes
__device__ __forceinline__ unsigned pack_pairs(float u) {
    unsigned pa = __float_as_uint(u) + 0x8000u;                 // cheap RN
    unsigned pb = (unsigned)__builtin_amdgcn_update_dpp(
        0, (int)pa, 0xB1 /*quad_perm [1,0,3,2]*/, 0xF, 0xF, false);
    // result: lo16 = pa[31:16], hi16 = pb[31:16]
    return __builtin_amdgcn_perm(pb, pa, 0x07060302);
}

__device__ __forceinline__ float dot2bf(unsigned a, unsigned b, float c) {
#if __has_builtin(__builtin_amdgcn_fdot2_f32_bf16)
    return __builtin_amdgcn_fdot2_f32_bf16(__builtin_bit_cast(bf16x2, a),
                                           __builtin_bit_cast(bf16x2, b),
                                           c, false);
#else
    float d = c;
    asm("v_dot2_f32_bf16 %0, %1, %2, %0" : "+v"(d) : "v"(a), "v"(b));
    return d;
#endif
}

__launch_bounds__(64, 1)
__global__ void crf_fwd_kernel(const float* __restrict__ emit,
                               const float* __restrict__ trans,
                               const float* __restrict__ strans,
                               const float* __restrict__ etrans,
                               const unsigned char* __restrict__ mask_u8,
                               float* __restrict__ out)
{
    const int lane = threadIdx.x;   // 0..63
    const int b    = blockIdx.x;

    // ---------- register-only preprocess (per wave) ----------
    float rowlse_v;
    {
        const float* rowp = trans + lane * CRF_N;
        float m = -1e30f;
        #pragma unroll 8
        for (int k = 0; k < CRF_N; ++k) m = fmaxf(m, rowp[k]);
        float s = 0.f;
        #pragma unroll 8
        for (int k = 0; k < CRF_N; ++k) s += __expf(rowp[k] - m);
        rowlse_v = m + __logf(s);
    }

    // pass 1: column max of tn (for this lane's label)
    float cmx = -1e30f;
    #pragma unroll
    for (int j = 0; j < CRF_N; ++j)
        cmx = fmaxf(cmx, trans[j * CRF_N + lane] - rlanef(rowlse_v, j));

    // pass 2: packed bf16 E pairs — Epk[m] = (E[2m][lane], E[2m+1][lane])
    unsigned Epk[32];
    #pragma unroll
    for (int m = 0; m < 32; ++m) {
        float e0 = __expf(trans[(2 * m)     * CRF_N + lane] - rlanef(rowlse_v, 2 * m)     - cmx);
        float e1 = __expf(trans[(2 * m + 1) * CRF_N + lane] - rlanef(rowlse_v, 2 * m + 1) - cmx);
        Epk[m] = bf16_rne(e0) | (bf16_rne(e1) << 16);
    }

    const float sn = wave_lse(strans[lane]);

    // ---- sequence length from mask (dtype-adaptive: bool bytes vs int32) ----
    int len;
    {
        int c8 = 0;
        #pragma unroll
        for (int q = 0; q < 4; ++q)
            c8 += (mask_u8[(size_t)b * CRF_T + q * 64 + lane] != 0) ? 1 : 0;
        for (int off = 1; off < 64; off <<= 1) c8 += __shfl_xor(c8, off);
        if (c8 >= 128) {
            len = c8;       // genuine bool bytes (len in [128,256])
        } else {
            const int* mi = (const int*)mask_u8;
            int ci = 0;
            #pragma unroll
            for (int q = 0; q < 4; ++q)
                ci += (mi[(size_t)b * CRF_T + q * 64 + lane] != 0) ? 1 : 0;
            for (int off = 1; off < 64; off <<= 1) ci += __shfl_xor(ci, off);
            len = ci;
        }
    }

    const float* eb = emit + (size_t)b * CRF_T * CRF_N;

    // ---------- init (t = 0) ----------
    float alpha0 = (strans[lane] - sn) + eb[lane];
    float c0 = rl0(alpha0);
    float u  = __expf(alpha0 - c0);   // lane 0: u = 1
    unsigned upi = pack_pairs(u);
    float R  = 1.0f;                  // rcp of previous step's u0
    float Pm = 1.0f;                  // running product of u0 (mantissa)
    int   Eacc = 0;                   // running exponent (base 2)

    // one step
#define CRF_STEP(EE, EE0)                                                   \
    {                                                                       \
        float ree = R * (EE);         /* ready before dot completes */      \
        float sc0 = R * (EE0);                                              \
        float a0 = 0.f, a1 = 0.f, a2 = 0.f, a3 = 0.f;                       \
        _Pragma("unroll")                                                   \
        for (int m2 = 0; m2 < 32; m2 += 4) {                                \
            unsigned w0 = (unsigned)__builtin_amdgcn_readlane((int)upi, 2 * m2 + 0); \
            unsigned w1 = (unsigned)__builtin_amdgcn_readlane((int)upi, 2 * m2 + 2); \
            unsigned w2 = (unsigned)__builtin_amdgcn_readlane((int)upi, 2 * m2 + 4); \
            unsigned w3 = (unsigned)__builtin_amdgcn_readlane((int)upi, 2 * m2 + 6); \
            a0 = dot2bf(w0, Epk[m2 + 0], a0);                               \
            a1 = dot2bf(w1, Epk[m2 + 1], a1);                               \
            a2 = dot2bf(w2, Epk[m2 + 2], a2);                               \
            a3 = dot2bf(w3, Epk[m2 + 3], a3);                               \
        }                                                                   \
        float s = (a0 + a1) + (a2 + a3);                                    \
        float s0 = rl0(s);                                                  \
        u = s * ree;                                                        \
        upi = pack_pairs(u);                                                \
        float u0 = s0 * sc0;          /* == lane-0 of u (assoc. diff) */    \
        R = __builtin_amdgcn_rcpf(u0);                                      \
        Pm *= u0;                                                           \
    }

    // ---------- main loop: groups of 4 with emission prefetch ----------
    float eN[4], eeC[4], ee0C[4];
    #pragma unroll
    for (int d = 0; d < 4; ++d) eN[d] = eb[(size_t)(1 + d) * CRF_N + lane];
    #pragma unroll
    for (int d = 0; d < 4; ++d) eeC[d] = __expf(eN[d] + cmx);
    #pragma unroll
    for (int d = 0; d < 4; ++d) ee0C[d] = rl0(eeC[d]);

    int t0 = 1;
    while (t0 + 4 <= len) {
        #pragma unroll
        for (int d = 0; d < 4; ++d) {
            int ti = t0 + 4 + d;
            ti = (ti < len) ? ti : (len - 1);
            eN[d] = eb[(size_t)ti * CRF_N + lane];
        }
        CRF_STEP(eeC[0], ee0C[0]); CRF_STEP(eeC[1], ee0C[1]);
        CRF_STEP(eeC[2], ee0C[2]); CRF_STEP(eeC[3], ee0C[3]);
        {
            int ex;
            Pm = frexpf(Pm, &ex);
            Eacc += ex;
        }
        #pragma unroll
        for (int d = 0; d < 4; ++d) eeC[d] = __expf(eN[d] + cmx);
        #pragma unroll
        for (int d = 0; d < 4; ++d) ee0C[d] = rl0(eeC[d]);
        t0 += 4;
    }
    {
        const int nrem = len - t0;   // wave-uniform, < 4
        #pragma unroll
        for (int d = 0; d < 4; ++d) {
            if (d >= nrem) break;
            CRF_STEP(eeC[d], ee0C[d]);
        }
    }
#undef CRF_STEP

    // ---------- final lse over labels + batch-sum ----------
    const float en = wave_lse(etrans[lane]);
    float Lacc = c0 + 0.6931471805599453f * (float)Eacc + __logf(Pm);
    float v = Lacc + __logf(u * R) + (etrans[lane] - en);
    float m = v;
    #pragma unroll
    for (int off = 1; off < 64; off <<= 1) m = fmaxf(m, __shfl_xor(m, off));
    float sum = __expf(v - m);
    #pragma unroll
    for (int off = 1; off < 64; off <<= 1) sum += __shfl_xor(sum, off);

    if (lane == 0) {
        atomicAdd(out, m + __logf(sum));
    }
}

extern "C" void kernel_launch(void* const* d_in, const int* in_sizes, int n_in,
                              void* d_out, int out_size, void* d_ws, size_t ws_size,
                              hipStream_t stream) {
    const float* emit   = (const float*)d_in[0];
    const float* trans  = (const float*)d_in[1];
    const float* strans = (const float*)d_in[2];
    const float* etrans = (const float*)d_in[3];
    const unsigned char* mask = (const unsigned char*)d_in[4];
    float* out = (float*)d_out;

    hipMemsetAsync(out, 0, sizeof(float), stream);
    crf_fwd_kernel<<<dim3(CRF_B), dim3(64), 0, stream>>>(
        emit, trans, strans, etrans, mask, out);
}